// Round 7
// baseline (608.099 us; speedup 1.0000x reference)
//
#include <hip/hip_runtime.h>
#include <stdint.h>

#define S_LEN 2048
#define HIDDEN_ 2048
#define NH 16
#define QR 1536
#define KVR 512
#define DN 128
#define DR 64
#define DQK 192
#define DV 128

typedef __attribute__((ext_vector_type(8))) short bf16x8;
typedef __attribute__((ext_vector_type(4))) float f32x4;
typedef __attribute__((ext_vector_type(16))) float f32x16;
typedef __attribute__((ext_vector_type(4))) unsigned short u16x4;
typedef unsigned short u16;
typedef unsigned int u32;

#define GLOAD_LDS16(g, l)                                                      \
    __builtin_amdgcn_global_load_lds(                                          \
        (const __attribute__((address_space(1))) void*)(g),                    \
        (__attribute__((address_space(3))) void*)(l), 16, 0, 0)

__device__ inline float bf2f(u16 x) {
    union { u32 u; float f; } v; v.u = ((u32)x) << 16; return v.f;
}
__device__ inline u16 f2bf(float f) {
    union { float f; u32 u; } v; v.f = f;
    u32 u = v.u;
    return (u16)((u + 0x7fffu + ((u >> 16) & 1u)) >> 16);
}

// ---------------------------------------------------------------------------
// f32 -> bf16 conversion.
// ---------------------------------------------------------------------------
__global__ void cvt_f2b(const float* __restrict__ src, u16* __restrict__ dst, int n)
{
    int i = (blockIdx.x * 256 + threadIdx.x) * 4;
    if (i + 3 < n) {
        float4 v = *(const float4*)(src + i);
        dst[i + 0] = f2bf(v.x);
        dst[i + 1] = f2bf(v.y);
        dst[i + 2] = f2bf(v.z);
        dst[i + 3] = f2bf(v.w);
    }
}

// ---------------------------------------------------------------------------
// Generic bf16 GEMM: C[M,N] = A[M,K] @ B[N,K]^T, f32 accumulate.
// global_load_lds width-16 staging, 128x128 tile, BK=32.
// ---------------------------------------------------------------------------
__global__ __launch_bounds__(256, 2)
void gemm_bt(const u16* __restrict__ A, const u16* __restrict__ B,
             void* __restrict__ Cv, int M, int N, int K, int out_f32)
{
    __shared__ u16 sA[128 * 32];
    __shared__ u16 sB[128 * 32];
    const int tid  = threadIdx.x;
    const int wave = tid >> 6;
    const int lane = tid & 63;
    const int l16  = lane & 15;
    const int quad = lane >> 4;
    const int m_blk = blockIdx.y * 128;
    const int n_blk = blockIdx.x * 128;
    const int wm = (wave >> 1) * 64;
    const int wn = (wave & 1) * 64;

    const f32x4 zero4 = {0.f, 0.f, 0.f, 0.f};
    f32x4 acc[4][4];
#pragma unroll
    for (int i = 0; i < 4; i++)
#pragma unroll
        for (int j = 0; j < 4; j++) acc[i][j] = zero4;

    const int srow = lane >> 2;
    const int scol = (lane & 3) * 8;

    for (int k0 = 0; k0 < K; k0 += 32) {
        __syncthreads();
#pragma unroll
        for (int p = 0; p < 2; p++) {
            const int rbase = wave * 32 + p * 16;
            const int row = rbase + srow;
            const u16* ga = A + (size_t)(m_blk + row) * K + k0 + scol;
            GLOAD_LDS16(ga, &sA[rbase * 32]);
            int brow = n_blk + row; if (brow >= N) brow = N - 1;
            const u16* gb = B + (size_t)brow * K + k0 + scol;
            GLOAD_LDS16(gb, &sB[rbase * 32]);
        }
        __syncthreads();

        bf16x8 af[4], bfr[4];
#pragma unroll
        for (int i = 0; i < 4; i++)
            af[i] = *(const bf16x8*)(sA + (wm + i * 16 + l16) * 32 + quad * 8);
#pragma unroll
        for (int j = 0; j < 4; j++)
            bfr[j] = *(const bf16x8*)(sB + (wn + j * 16 + l16) * 32 + quad * 8);
#pragma unroll
        for (int i = 0; i < 4; i++)
#pragma unroll
            for (int j = 0; j < 4; j++)
                acc[i][j] = __builtin_amdgcn_mfma_f32_16x16x32_bf16(
                    af[i], bfr[j], acc[i][j], 0, 0, 0);
    }

#pragma unroll
    for (int i = 0; i < 4; i++)
#pragma unroll
        for (int j = 0; j < 4; j++)
#pragma unroll
            for (int r = 0; r < 4; r++) {
                int mrow = m_blk + wm + i * 16 + quad * 4 + r;
                int ncol = n_blk + wn + j * 16 + l16;
                if (ncol < N) {
                    if (out_f32)
                        ((float*)Cv)[(size_t)mrow * N + ncol] = acc[i][j][r];
                    else
                        ((u16*)Cv)[(size_t)mrow * N + ncol] = f2bf(acc[i][j][r]);
                }
            }
}

// ---------------------------------------------------------------------------
// RMSNorm over bf16 input rows; weight is the original f32 tensor.
// ---------------------------------------------------------------------------
__global__ void rmsnorm_k(const u16* __restrict__ X, const float* __restrict__ W,
                          u16* __restrict__ Y, int in_stride, int len, int out_stride)
{
    const int row = blockIdx.x;
    const u16* x = X + (size_t)row * in_stride;
    u16* y = Y + (size_t)row * out_stride;
    float ss = 0.f;
    for (int i = threadIdx.x; i < len; i += 256) { float v = bf2f(x[i]); ss += v * v; }
#pragma unroll
    for (int off = 32; off; off >>= 1) ss += __shfl_down(ss, off, 64);
    __shared__ float red[4];
    if ((threadIdx.x & 63) == 0) red[threadIdx.x >> 6] = ss;
    __syncthreads();
    float tot = red[0] + red[1] + red[2] + red[3];
    float inv = 1.0f / sqrtf(tot / (float)len + 1e-6f);
    for (int i = threadIdx.x; i < len; i += 256)
        y[i] = f2bf(W[i] * bf2f(x[i]) * inv);
}

// ---------------------------------------------------------------------------
// RoPE + repack Q/K into per-head contiguous layouts:
//   Q [H][S][192], K [H][S][192]
// ---------------------------------------------------------------------------
__global__ void rope_repack(const u16* __restrict__ q,      // [S][H*192]
                            const u16* __restrict__ kvb,    // [S][H*256]
                            const u16* __restrict__ kva_pe, // [S][*] stride kva_stride
                            int kva_stride,
                            u16* __restrict__ Q, u16* __restrict__ Kf)
{
    const int s = blockIdx.x;
    const float pos = (float)s;
    const int t = threadIdx.x;
    __shared__ float cs[64], sn[64];
    __shared__ u16 kpe_r[64];
    if (t < 64) {
        int jf = t & 31;
        float freq = powf(10000.f, -(float)(2 * jf) / 64.f);
        float ang = pos * freq;
        cs[t] = cosf(ang);
        sn[t] = sinf(ang);
    }
    __syncthreads();
    if (t < 64) {
        int j = t;
        float x = bf2f(kva_pe[(size_t)s * kva_stride + j]);
        float other = (j < 32) ? -bf2f(kva_pe[(size_t)s * kva_stride + j + 32])
                               :  bf2f(kva_pe[(size_t)s * kva_stride + j - 32]);
        kpe_r[j] = f2bf(x * cs[j] + other * sn[j]);
    }
    __syncthreads();

    for (int idx = t; idx < NH * DQK; idx += 256) {
        int h = idx / DQK, d = idx % DQK;
        const size_t qrow = (size_t)s * (NH * DQK) + h * DQK;
        u16 qv;
        if (d < DN) qv = q[qrow + d];
        else {
            int j = d - DN;
            float x = bf2f(q[qrow + DN + j]);
            float other = (j < 32) ? -bf2f(q[qrow + DN + j + 32])
                                   :  bf2f(q[qrow + DN + j - 32]);
            qv = f2bf(x * cs[j] + other * sn[j]);
        }
        Q[((size_t)h * S_LEN + s) * DQK + d] = qv;
        u16 kv;
        if (d < DN) kv = kvb[(size_t)s * (NH * 256) + h * 256 + d];
        else        kv = kpe_r[d - DN];
        Kf[((size_t)h * S_LEN + s) * DQK + d] = kv;
    }
}

// ---------------------------------------------------------------------------
// V transpose straight out of kvb: Vt[h][d][s] = kvb[s][h*256+128+d].
// ---------------------------------------------------------------------------
__global__ void transpose_v(const u16* __restrict__ kvb, u16* __restrict__ Vt)
{
    __shared__ u16 tile[64][72];
    const int h  = blockIdx.z;
    const int s0 = blockIdx.x * 64;
    const int d0 = blockIdx.y * 64;
    const int t  = threadIdx.x;
#pragma unroll
    for (int p = 0; p < 2; p++) {
        int c = p * 256 + t;
        int r = c >> 3, col = (c & 7) * 8;
        *(bf16x8*)&tile[r][col] =
            *(const bf16x8*)&kvb[(size_t)(s0 + r) * (NH * 256) + h * 256 + 128 + d0 + col];
    }
    __syncthreads();
#pragma unroll
    for (int p = 0; p < 2; p++) {
        int c = p * 256 + t;
        int dr = c >> 3, sc = (c & 7) * 8;
        bf16x8 v;
#pragma unroll
        for (int j = 0; j < 8; j++) v[j] = (short)tile[sc + j][dr];
        *(bf16x8*)&Vt[((size_t)h * DV + d0 + dr) * S_LEN + s0 + sc] = v;
    }
}

// ---------------------------------------------------------------------------
// Causal flash attention on 32x32x16 MFMA.
// Block = 4 waves x 32 q-rows = 128-row strip; grid (16, NH) = 256 blocks.
// Per 64-col k-tile: 24 QK MFMA -> S^T (q = lane&31, k on regs/half-wave),
// softmax with ONE shfl_xor(32) for max + one for sum, in-register P
// C->B-operand transform via 8 shfl_xor (no LDS round-trip), 16 PV MFMA.
// K double-buffered in LDS via global_load_lds (48 KB); V^T fragments
// gathered from global (wave-invariant addresses -> L1 serves 3 of 4 waves),
// issued right after QK so softmax hides their latency.
// ---------------------------------------------------------------------------
__global__ __launch_bounds__(256, 1)
void mla_attn(const u16* __restrict__ Q, const u16* __restrict__ Kf,
              const u16* __restrict__ Vt, u16* __restrict__ attn)
{
    const int h    = blockIdx.y;
    const int s    = blockIdx.x;         // 128-row strip
    const int wave = threadIdx.x >> 6;
    const int lane = threadIdx.x & 63;
    const int l32  = lane & 31;
    const int hw   = lane >> 5;
    const int q0   = s * 128 + wave * 32;
    const int qrow = q0 + l32;

    const u16* Qh  = Q  + (size_t)h * S_LEN * DQK;
    const u16* Kh  = Kf + (size_t)h * S_LEN * DQK;
    const u16* Vth = Vt + (size_t)h * DV * S_LEN;

    // K tile 64 rows x 192 d, chunk (cg,row) at sK[b][(cg*64+row)*8], cg=d/8
    __shared__ u16 sK[2][24 * 64 * 8];   // 2 x 24 KB

    bf16x8 qf[12];
#pragma unroll
    for (int st = 0; st < 12; st++)
        qf[st] = *(const bf16x8*)(Qh + (size_t)qrow * DQK + st * 16 + hw * 8);

    f32x16 oacc[4];
#pragma unroll
    for (int t = 0; t < 4; t++)
#pragma unroll
        for (int r = 0; r < 16; r++) oacc[t][r] = 0.f;
    float mrow = -INFINITY, lrow = 0.f;

    const float scale = 0.07216878364870323f;  // 192^-0.5
    const int T = 2 * s + 2;                   // 64-col tiles (block-uniform)

    auto stage = [&](int buf, int c0) {
#pragma unroll
        for (int g = 0; g < 6; g++) {
            int c = g * 256 + wave * 64 + lane;
            int row = c & 63, cg = c >> 6;
            GLOAD_LDS16(Kh + (size_t)(c0 + row) * DQK + cg * 8,
                        &sK[buf][(g * 256 + wave * 64) * 8]);
        }
    };

    stage(0, 0);

    for (int kt = 0; kt < T; kt++) {
        const int c0  = kt * 64;
        const int cur = kt & 1;
        __syncthreads();
        if (kt + 1 < T) stage(cur ^ 1, c0 + 64);

        if (c0 <= q0 + 31) {
            // QK^T transposed: A=K (m = k-col), B=Q (n = q-row = lane&31)
            f32x16 sc0, sc1;
#pragma unroll
            for (int r = 0; r < 16; r++) { sc0[r] = 0.f; sc1[r] = 0.f; }
#pragma unroll
            for (int st = 0; st < 12; st++) {
                bf16x8 ka = *(const bf16x8*)&sK[cur][((st * 2 + hw) * 64 + l32) * 8];
                bf16x8 kb = *(const bf16x8*)&sK[cur][((st * 2 + hw) * 64 + 32 + l32) * 8];
                sc0 = __builtin_amdgcn_mfma_f32_32x32x16_bf16(ka, qf[st], sc0, 0, 0, 0);
                sc1 = __builtin_amdgcn_mfma_f32_32x32x16_bf16(kb, qf[st], sc1, 0, 0, 0);
            }
            // V^T fragments for this tile (global gathers, latency hidden below)
            bf16x8 vf[4][4];
#pragma unroll
            for (int t = 0; t < 4; t++)
#pragma unroll
                for (int kh = 0; kh < 4; kh++)
                    vf[t][kh] = *(const bf16x8*)(Vth + (size_t)(t * 32 + l32) * S_LEN
                                                 + c0 + kh * 16 + hw * 8);

            const bool full = (c0 + 63 <= q0);
            float vv0[16], vv1[16];
#pragma unroll
            for (int r = 0; r < 16; r++) {
                vv0[r] = sc0[r] * scale;
                vv1[r] = sc1[r] * scale;
            }
            if (!full) {
#pragma unroll
                for (int r = 0; r < 16; r++) {
                    int kg = c0 + (r & 3) + 8 * (r >> 2) + 4 * hw;
                    if (kg > qrow)      vv0[r] = -INFINITY;
                    if (kg + 32 > qrow) vv1[r] = -INFINITY;
                }
            }
            float lm = vv0[0];
#pragma unroll
            for (int r = 1; r < 16; r++) lm = fmaxf(lm, vv0[r]);
#pragma unroll
            for (int r = 0; r < 16; r++) lm = fmaxf(lm, vv1[r]);
            lm = fmaxf(lm, __shfl_xor(lm, 32, 64));
            const float mnew  = fmaxf(mrow, lm);
            const float alpha = __expf(mrow - mnew);
            float rs = 0.f;
#pragma unroll
            for (int r = 0; r < 16; r++) { vv0[r] = __expf(vv0[r] - mnew); rs += vv0[r]; }
#pragma unroll
            for (int r = 0; r < 16; r++) { vv1[r] = __expf(vv1[r] - mnew); rs += vv1[r]; }
            rs += __shfl_xor(rs, 32, 64);
            lrow = lrow * alpha + rs;
            mrow = mnew;
#pragma unroll
            for (int t = 0; t < 4; t++) oacc[t] *= alpha;

            // pack P: pg[M] = bf16 of k-run (8M+4hw .. +3), M = 8-run index
            u16x4 pg[8];
#pragma unroll
            for (int g = 0; g < 4; g++)
#pragma unroll
                for (int r2 = 0; r2 < 4; r2++) {
                    pg[g][r2]     = f2bf(vv0[g * 4 + r2]);
                    pg[4 + g][r2] = f2bf(vv1[g * 4 + r2]);
                }
            // C->B-operand transform in-register: B-frag(kh) j -> k=16kh+8hw+j
            bf16x8 pf[4];
#pragma unroll
            for (int kh = 0; kh < 4; kh++) {
                u16x4 own  = pg[2 * kh + hw];
                u16x4 send = pg[2 * kh + (hw ^ 1)];
                u32 sa = ((u32)send[0]) | ((u32)send[1] << 16);
                u32 sb = ((u32)send[2]) | ((u32)send[3] << 16);
                u32 ra = (u32)__shfl_xor((int)sa, 32, 64);
                u32 rb = (u32)__shfl_xor((int)sb, 32, 64);
                u16x4 rec;
                rec[0] = (u16)(ra & 0xffff); rec[1] = (u16)(ra >> 16);
                rec[2] = (u16)(rb & 0xffff); rec[3] = (u16)(rb >> 16);
                u16x4 lo = hw ? rec : own;
                u16x4 hi = hw ? own : rec;
                bf16x8 p;
#pragma unroll
                for (int j = 0; j < 4; j++) { p[j] = (short)lo[j]; p[4 + j] = (short)hi[j]; }
                pf[kh] = p;
            }
            // PV: out^T[d][q], A=V^T (m=d), B=P
#pragma unroll
            for (int t = 0; t < 4; t++)
#pragma unroll
                for (int kh = 0; kh < 4; kh++)
                    oacc[t] = __builtin_amdgcn_mfma_f32_32x32x16_bf16(
                        vf[t][kh], pf[kh], oacc[t], 0, 0, 0);
        }
    }

    const float linv = 1.0f / lrow;
#pragma unroll
    for (int t = 0; t < 4; t++)
#pragma unroll
        for (int g = 0; g < 4; g++) {
            u16x4 ov;
#pragma unroll
            for (int r2 = 0; r2 < 4; r2++) ov[r2] = f2bf(oacc[t][g * 4 + r2] * linv);
            *(u16x4*)&attn[(size_t)qrow * (NH * DV) + h * DV + t * 32 + 8 * g + 4 * hw] = ov;
        }
}

// ---------------------------------------------------------------------------
extern "C" void kernel_launch(void* const* d_in, const int* in_sizes, int n_in,
                              void* d_out, int out_size, void* d_ws, size_t ws_size,
                              hipStream_t stream)
{
    const float* hid      = (const float*)d_in[0];
    // d_in[1] = position_ids (== arange(s)); sequence index used directly.
    const float* q_a_w    = (const float*)d_in[2];
    const float* q_a_ln_w = (const float*)d_in[3];
    const float* q_b_w    = (const float*)d_in[4];
    const float* kv_a_w   = (const float*)d_in[5];
    const float* kv_a_ln_w= (const float*)d_in[6];
    const float* kv_b_w   = (const float*)d_in[7];
    const float* o_w      = (const float*)d_in[8];

    const int NQKV = QR + KVR + DR;   // 2112: merged q_a_w ++ kv_a_w rows

    char* base = (char*)d_ws;
    u16* qkvaw_b = (u16*)(base + 0);          //  8,650,752  [2112,2048]
    u16* qbw_b   = (u16*)(base + 8650752);    //  9,437,184  [3072,1536]
    u16* kvbw_b  = (u16*)(base + 18087936);   //  4,194,304  [4096,512]
    u16* ow_b    = (u16*)(base + 22282240);   //  8,388,608  [2048,2048]
    u16* hid_b   = (u16*)(base + 30670848);   //  8,388,608  [2048,2048]
    u16* qkv_a   = (u16*)(base + 39059456);   //  8,650,752  [2048,2112]
    u16* q_n     = (u16*)(base + 47710208);   //  6,291,456  [2048,1536]
    u16* ckv     = (u16*)(base + 54001664);   //  2,097,152  [2048,512]
    u16* qb      = (u16*)(base + 56098816);   // 12,582,912  [2048,3072]
    u16* kvb     = (u16*)(base + 68681728);   // 16,777,216  [2048,4096]
    u16* Qb      = (u16*)(base + 85458944);   // 12,582,912  [16][2048][192]
    u16* Kb      = (u16*)(base + 98041856);   // 12,582,912
    u16* Vtb     = (u16*)(base + 110624768);  //  8,388,608  [16][128][2048]
    u16* attnb   = (u16*)(base + 39059456);   // reuse qkv_a (dead after rope)

    // 0) convert f32 inputs/weights to bf16
    cvt_f2b<<<HIDDEN_ * S_LEN / 1024, 256, 0, stream>>>(hid, hid_b, HIDDEN_ * S_LEN);
    cvt_f2b<<<QR * HIDDEN_ / 1024, 256, 0, stream>>>(q_a_w, qkvaw_b, QR * HIDDEN_);
    cvt_f2b<<<(KVR + DR) * HIDDEN_ / 1024, 256, 0, stream>>>(
        kv_a_w, qkvaw_b + (size_t)QR * HIDDEN_, (KVR + DR) * HIDDEN_);
    cvt_f2b<<<NH * DQK * QR / 1024, 256, 0, stream>>>(q_b_w, qbw_b, NH * DQK * QR);
    cvt_f2b<<<NH * 256 * KVR / 1024, 256, 0, stream>>>(kv_b_w, kvbw_b, NH * 256 * KVR);
    cvt_f2b<<<HIDDEN_ * NH * DV / 1024, 256, 0, stream>>>(o_w, ow_b, HIDDEN_ * NH * DV);

    // 1) qkv_a = hidden @ [q_a_w; kv_a_w]^T   [2048,2112]
    gemm_bt<<<dim3((NQKV + 127) / 128, S_LEN / 128), 256, 0, stream>>>(
        hid_b, qkvaw_b, qkv_a, S_LEN, NQKV, HIDDEN_, 0);
    // 2) q_n = rmsnorm(qkv_a[:, :1536])
    rmsnorm_k<<<S_LEN, 256, 0, stream>>>(qkv_a, q_a_ln_w, q_n, NQKV, QR, QR);
    // 3) ckv = rmsnorm(qkv_a[:, 1536:2048])
    rmsnorm_k<<<S_LEN, 256, 0, stream>>>(qkv_a + QR, kv_a_ln_w, ckv, NQKV, KVR, KVR);
    // 4) qb = q_n @ q_b_w^T           [2048,3072]
    gemm_bt<<<dim3(NH * DQK / 128, S_LEN / 128), 256, 0, stream>>>(
        q_n, qbw_b, qb, S_LEN, NH * DQK, QR, 0);
    // 5) kvb = ckv @ kv_b_w^T         [2048,4096]
    gemm_bt<<<dim3(NH * 256 / 128, S_LEN / 128), 256, 0, stream>>>(
        ckv, kvbw_b, kvb, S_LEN, NH * 256, KVR, 0);
    // 6) rope + repack Q/K (k_pe = qkv_a cols 2048..2111)
    rope_repack<<<S_LEN, 256, 0, stream>>>(qb, kvb, qkv_a + QR + KVR, NQKV, Qb, Kb);
    // 6b) V transpose: Vt[h][d][s]
    transpose_v<<<dim3(S_LEN / 64, DV / 64, NH), 256, 0, stream>>>(kvb, Vtb);
    // 7) causal flash attention -> attnb [2048, 2048]
    mla_attn<<<dim3(16, NH), 256, 0, stream>>>(Qb, Kb, Vtb, attnb);
    // 8) out = attnb @ o_w^T          [2048,2048], f32 output
    gemm_bt<<<dim3(HIDDEN_ / 128, S_LEN / 128), 256, 0, stream>>>(
        attnb, ow_b, (float*)d_out, S_LEN, HIDDEN_, HIDDEN_, 1);
}

// Round 8
// 402.468 us; speedup vs baseline: 1.5109x; 1.5109x over previous
//
#include <hip/hip_runtime.h>
#include <stdint.h>

#define S_LEN 2048
#define HIDDEN_ 2048
#define NH 16
#define QR 1536
#define KVR 512
#define DN 128
#define DR 64
#define DQK 192
#define DV 128

typedef __attribute__((ext_vector_type(8))) short bf16x8;
typedef __attribute__((ext_vector_type(4))) float f32x4;
typedef __attribute__((ext_vector_type(4))) unsigned short u16x4;
typedef unsigned short u16;
typedef unsigned int u32;

#define GLOAD_LDS16(g, l)                                                      \
    __builtin_amdgcn_global_load_lds(                                          \
        (const __attribute__((address_space(1))) void*)(g),                    \
        (__attribute__((address_space(3))) void*)(l), 16, 0, 0)

__device__ inline float bf2f(u16 x) {
    union { u32 u; float f; } v; v.u = ((u32)x) << 16; return v.f;
}
__device__ inline u16 f2bf(float f) {
    union { float f; u32 u; } v; v.f = f;
    u32 u = v.u;
    return (u16)((u + 0x7fffu + ((u >> 16) & 1u)) >> 16);
}

// ---------------------------------------------------------------------------
// Merged f32 -> bf16 conversion: one launch, grid.y selects tensor.
// ---------------------------------------------------------------------------
__global__ void cvt_multi(const float* s0, u16* d0, int n0,
                          const float* s1, u16* d1, int n1,
                          const float* s2, u16* d2, int n2,
                          const float* s3, u16* d3, int n3,
                          const float* s4, u16* d4, int n4,
                          const float* s5, u16* d5, int n5)
{
    const float* src; u16* dst; int n;
    switch (blockIdx.y) {
        case 0: src = s0; dst = d0; n = n0; break;
        case 1: src = s1; dst = d1; n = n1; break;
        case 2: src = s2; dst = d2; n = n2; break;
        case 3: src = s3; dst = d3; n = n3; break;
        case 4: src = s4; dst = d4; n = n4; break;
        default: src = s5; dst = d5; n = n5; break;
    }
    int i = (blockIdx.x * 256 + threadIdx.x) * 4;
    if (i + 3 < n) {
        float4 v = *(const float4*)(src + i);
        dst[i + 0] = f2bf(v.x);
        dst[i + 1] = f2bf(v.y);
        dst[i + 2] = f2bf(v.z);
        dst[i + 3] = f2bf(v.w);
    }
}

// ---------------------------------------------------------------------------
// Generic bf16 GEMM: C[M,N] = A[M,K] @ B[N,K]^T, f32 accumulate.
// global_load_lds width-16 staging, 128x128 tile, BK=32.
// launch_bounds(256,3): target 3 blocks/CU (m97 ran 874 TF at ~3 blk/CU;
// (256,2) capped us at 2 and forgoes the implicit wave-overlap that hides
// the barrier drain).
// ---------------------------------------------------------------------------
__global__ __launch_bounds__(256, 3)
void gemm_bt(const u16* __restrict__ A, const u16* __restrict__ B,
             void* __restrict__ Cv, int M, int N, int K, int out_f32)
{
    __shared__ u16 sA[128 * 32];
    __shared__ u16 sB[128 * 32];
    const int tid  = threadIdx.x;
    const int wave = tid >> 6;
    const int lane = tid & 63;
    const int l16  = lane & 15;
    const int quad = lane >> 4;
    const int m_blk = blockIdx.y * 128;
    const int n_blk = blockIdx.x * 128;
    const int wm = (wave >> 1) * 64;
    const int wn = (wave & 1) * 64;

    const f32x4 zero4 = {0.f, 0.f, 0.f, 0.f};
    f32x4 acc[4][4];
#pragma unroll
    for (int i = 0; i < 4; i++)
#pragma unroll
        for (int j = 0; j < 4; j++) acc[i][j] = zero4;

    const int srow = lane >> 2;
    const int scol = (lane & 3) * 8;

    for (int k0 = 0; k0 < K; k0 += 32) {
        __syncthreads();
#pragma unroll
        for (int p = 0; p < 2; p++) {
            const int rbase = wave * 32 + p * 16;
            const int row = rbase + srow;
            const u16* ga = A + (size_t)(m_blk + row) * K + k0 + scol;
            GLOAD_LDS16(ga, &sA[rbase * 32]);
            int brow = n_blk + row; if (brow >= N) brow = N - 1;
            const u16* gb = B + (size_t)brow * K + k0 + scol;
            GLOAD_LDS16(gb, &sB[rbase * 32]);
        }
        __syncthreads();

        bf16x8 af[4], bfr[4];
#pragma unroll
        for (int i = 0; i < 4; i++)
            af[i] = *(const bf16x8*)(sA + (wm + i * 16 + l16) * 32 + quad * 8);
#pragma unroll
        for (int j = 0; j < 4; j++)
            bfr[j] = *(const bf16x8*)(sB + (wn + j * 16 + l16) * 32 + quad * 8);
#pragma unroll
        for (int i = 0; i < 4; i++)
#pragma unroll
            for (int j = 0; j < 4; j++)
                acc[i][j] = __builtin_amdgcn_mfma_f32_16x16x32_bf16(
                    af[i], bfr[j], acc[i][j], 0, 0, 0);
    }

#pragma unroll
    for (int i = 0; i < 4; i++)
#pragma unroll
        for (int j = 0; j < 4; j++)
#pragma unroll
            for (int r = 0; r < 4; r++) {
                int mrow = m_blk + wm + i * 16 + quad * 4 + r;
                int ncol = n_blk + wn + j * 16 + l16;
                if (ncol < N) {
                    if (out_f32)
                        ((float*)Cv)[(size_t)mrow * N + ncol] = acc[i][j][r];
                    else
                        ((u16*)Cv)[(size_t)mrow * N + ncol] = f2bf(acc[i][j][r]);
                }
            }
}

// ---------------------------------------------------------------------------
// Merged RMSNorm: grid (S_LEN, 2). y==0: q (len 1536), y==1: kv (len 512).
// ---------------------------------------------------------------------------
__global__ void rmsnorm2_k(const u16* __restrict__ X0, const float* __restrict__ W0,
                           u16* __restrict__ Y0,
                           const u16* __restrict__ X1, const float* __restrict__ W1,
                           u16* __restrict__ Y1, int in_stride)
{
    const u16* X; const float* W; u16* Y; int len, out_stride;
    if (blockIdx.y == 0) { X = X0; W = W0; Y = Y0; len = QR;  out_stride = QR; }
    else                 { X = X1; W = W1; Y = Y1; len = KVR; out_stride = KVR; }
    const int row = blockIdx.x;
    const u16* x = X + (size_t)row * in_stride;
    u16* y = Y + (size_t)row * out_stride;
    float ss = 0.f;
    for (int i = threadIdx.x; i < len; i += 256) { float v = bf2f(x[i]); ss += v * v; }
#pragma unroll
    for (int off = 32; off; off >>= 1) ss += __shfl_down(ss, off, 64);
    __shared__ float red[4];
    if ((threadIdx.x & 63) == 0) red[threadIdx.x >> 6] = ss;
    __syncthreads();
    float tot = red[0] + red[1] + red[2] + red[3];
    float inv = 1.0f / sqrtf(tot / (float)len + 1e-6f);
    for (int i = threadIdx.x; i < len; i += 256)
        y[i] = f2bf(W[i] * bf2f(x[i]) * inv);
}

// ---------------------------------------------------------------------------
// RoPE + repack Q/K into per-head contiguous layouts:
//   Q [H][S][192], K [H][S][192]
// ---------------------------------------------------------------------------
__global__ void rope_repack(const u16* __restrict__ q,      // [S][H*192]
                            const u16* __restrict__ kvb,    // [S][H*256]
                            const u16* __restrict__ kva_pe, // [S][*] stride kva_stride
                            int kva_stride,
                            u16* __restrict__ Q, u16* __restrict__ Kf)
{
    const int s = blockIdx.x;
    const float pos = (float)s;
    const int t = threadIdx.x;
    __shared__ float cs[64], sn[64];
    __shared__ u16 kpe_r[64];
    if (t < 64) {
        int jf = t & 31;
        float freq = powf(10000.f, -(float)(2 * jf) / 64.f);
        float ang = pos * freq;
        cs[t] = cosf(ang);
        sn[t] = sinf(ang);
    }
    __syncthreads();
    if (t < 64) {
        int j = t;
        float x = bf2f(kva_pe[(size_t)s * kva_stride + j]);
        float other = (j < 32) ? -bf2f(kva_pe[(size_t)s * kva_stride + j + 32])
                               :  bf2f(kva_pe[(size_t)s * kva_stride + j - 32]);
        kpe_r[j] = f2bf(x * cs[j] + other * sn[j]);
    }
    __syncthreads();

    for (int idx = t; idx < NH * DQK; idx += 256) {
        int h = idx / DQK, d = idx % DQK;
        const size_t qrow = (size_t)s * (NH * DQK) + h * DQK;
        u16 qv;
        if (d < DN) qv = q[qrow + d];
        else {
            int j = d - DN;
            float x = bf2f(q[qrow + DN + j]);
            float other = (j < 32) ? -bf2f(q[qrow + DN + j + 32])
                                   :  bf2f(q[qrow + DN + j - 32]);
            qv = f2bf(x * cs[j] + other * sn[j]);
        }
        Q[((size_t)h * S_LEN + s) * DQK + d] = qv;
        u16 kv;
        if (d < DN) kv = kvb[(size_t)s * (NH * 256) + h * 256 + d];
        else        kv = kpe_r[d - DN];
        Kf[((size_t)h * S_LEN + s) * DQK + d] = kv;
    }
}

// ---------------------------------------------------------------------------
// V transpose straight out of kvb: Vt[h][d][s] = kvb[s][h*256+128+d].
// ---------------------------------------------------------------------------
__global__ void transpose_v(const u16* __restrict__ kvb, u16* __restrict__ Vt)
{
    __shared__ u16 tile[64][72];
    const int h  = blockIdx.z;
    const int s0 = blockIdx.x * 64;
    const int d0 = blockIdx.y * 64;
    const int t  = threadIdx.x;
#pragma unroll
    for (int p = 0; p < 2; p++) {
        int c = p * 256 + t;
        int r = c >> 3, col = (c & 7) * 8;
        *(bf16x8*)&tile[r][col] =
            *(const bf16x8*)&kvb[(size_t)(s0 + r) * (NH * 256) + h * 256 + 128 + d0 + col];
    }
    __syncthreads();
#pragma unroll
    for (int p = 0; p < 2; p++) {
        int c = p * 256 + t;
        int dr = c >> 3, sc = (c & 7) * 8;
        bf16x8 v;
#pragma unroll
        for (int j = 0; j < 8; j++) v[j] = (short)tile[sc + j][dr];
        *(bf16x8*)&Vt[((size_t)h * DV + d0 + dr) * S_LEN + s0 + sc] = v;
    }
}

// ---------------------------------------------------------------------------
// Causal flash attention, S^T-layout softmax (round-6 verified: 111.7 us).
// QK^T computed TRANSPOSED (A=K, B=Q) so lane's l16 = q-row, quads/regs = k.
// Row softmax: local max/sum over 8 regs + 2 shfl_xor. m/l/alpha scalar per
// lane. PV: A=V^T-frag, B=P-frag -> out^T in regs. Double-buffered K/V
// staging via global_load_lds (chunk-transposed LDS layout).
// Grid (32, NH); heads 0-7 strip=bx, heads 8-15 strip=31-bx (CU pairing).
// ---------------------------------------------------------------------------
__global__ __launch_bounds__(256, 2)
void mla_attn(const u16* __restrict__ Q, const u16* __restrict__ Kf,
              const u16* __restrict__ Vt, u16* __restrict__ attn)
{
    const int h     = blockIdx.y;
    const int strip = (h < 8) ? blockIdx.x : (31 - blockIdx.x);
    const int wave  = threadIdx.x >> 6;
    const int lane  = threadIdx.x & 63;
    const int l16   = lane & 15;
    const int quad  = lane >> 4;
    const int q0    = strip * 64 + wave * 16;
    const int qrow  = q0 + l16;          // this lane's q row

    const u16* Qh  = Q  + (size_t)h * S_LEN * DQK;
    const u16* Kh  = Kf + (size_t)h * S_LEN * DQK;
    const u16* Vth = Vt + (size_t)h * DV * S_LEN;

    __shared__ u16 sK[2][24 * 32 * 8];    // 2 x 12 KB
    __shared__ u16 sV[2][4 * 128 * 8];    // 2 x  8 KB
    __shared__ u16 pbuf[4][16][36];       // 4.5 KB
    u16 (*pb)[36] = pbuf[wave];

    bf16x8 qf[6];
#pragma unroll
    for (int st = 0; st < 6; st++)
        qf[st] = *(const bf16x8*)(Qh + (size_t)qrow * DQK + st * 32 + quad * 8);

    const f32x4 zero4 = {0.f, 0.f, 0.f, 0.f};
    f32x4 oacc[8];
#pragma unroll
    for (int t = 0; t < 8; t++) oacc[t] = zero4;
    float mrow = -INFINITY, lrow = 0.f;

    const float scale = 0.07216878364870323f;  // 192^-0.5
    const int T = 2 * strip + 2;               // block-uniform tile count

    auto stage = [&](int buf, int c0) {
#pragma unroll
        for (int g = 0; g < 3; g++) {
            int c = g * 256 + wave * 64 + lane;
            int row = c & 31, cg = c >> 5;
            GLOAD_LDS16(Kh + (size_t)(c0 + row) * DQK + cg * 8,
                        &sK[buf][(g * 256 + wave * 64) * 8]);
        }
#pragma unroll
        for (int g = 0; g < 2; g++) {
            int c = g * 256 + wave * 64 + lane;
            int d = c & 127, cg = c >> 7;
            GLOAD_LDS16(Vth + (size_t)d * S_LEN + c0 + cg * 8,
                        &sV[buf][(g * 256 + wave * 64) * 8]);
        }
    };

    stage(0, 0);   // prologue: tile 0 into buffer 0

    for (int kt = 0; kt < T; kt++) {
        const int c0  = kt * 32;
        const int cur = kt & 1;
        __syncthreads();
        if (kt + 1 < T) stage(cur ^ 1, c0 + 32);

        if (c0 <= q0 + 15) {
            // S^T: s0/s1 reg r, lane(quad,l16) = S^T[k=c0+(16?)+quad*4+r][q=qrow]
            f32x4 s0 = zero4, s1 = zero4;
#pragma unroll
            for (int st = 0; st < 6; st++) {
                bf16x8 k0 = *(const bf16x8*)&sK[cur][((st * 4 + quad) * 32 + l16) * 8];
                bf16x8 k1 = *(const bf16x8*)&sK[cur][((st * 4 + quad) * 32 + 16 + l16) * 8];
                s0 = __builtin_amdgcn_mfma_f32_16x16x32_bf16(k0, qf[st], s0, 0, 0, 0);
                s1 = __builtin_amdgcn_mfma_f32_16x16x32_bf16(k1, qf[st], s1, 0, 0, 0);
            }
            bf16x8 vfr[8];
#pragma unroll
            for (int t = 0; t < 8; t++)
                vfr[t] = *(const bf16x8*)&sV[cur][(quad * 128 + t * 16 + l16) * 8];

            const bool full = (c0 + 31 <= q0);
            float v0[4], v1[4];
#pragma unroll
            for (int r = 0; r < 4; r++) {
                v0[r] = s0[r] * scale;
                v1[r] = s1[r] * scale;
                if (!full) {
                    if (c0 + quad * 4 + r > qrow)      v0[r] = -INFINITY;
                    if (c0 + 16 + quad * 4 + r > qrow) v1[r] = -INFINITY;
                }
            }
            float lm = fmaxf(fmaxf(fmaxf(v0[0], v0[1]), fmaxf(v0[2], v0[3])),
                             fmaxf(fmaxf(v1[0], v1[1]), fmaxf(v1[2], v1[3])));
            lm = fmaxf(lm, __shfl_xor(lm, 16, 64));
            lm = fmaxf(lm, __shfl_xor(lm, 32, 64));
            const float mnew  = fmaxf(mrow, lm);
            const float alpha = __expf(mrow - mnew);
            float p0[4], p1[4], rs = 0.f;
#pragma unroll
            for (int r = 0; r < 4; r++) {
                p0[r] = __expf(v0[r] - mnew);
                p1[r] = __expf(v1[r] - mnew);
                rs += p0[r] + p1[r];
            }
            rs += __shfl_xor(rs, 16, 64);
            rs += __shfl_xor(rs, 32, 64);
            lrow = lrow * alpha + rs;
            mrow = mnew;
#pragma unroll
            for (int t = 0; t < 8; t++) oacc[t] *= alpha;

            u16x4 pk0, pk1;
#pragma unroll
            for (int r = 0; r < 4; r++) { pk0[r] = f2bf(p0[r]); pk1[r] = f2bf(p1[r]); }
            *(u16x4*)&pb[l16][quad * 4]      = pk0;   // P[q=l16][k=quad*4+r]
            *(u16x4*)&pb[l16][16 + quad * 4] = pk1;
            asm volatile("s_waitcnt lgkmcnt(0)" ::: "memory");
            bf16x8 pfrag = *(const bf16x8*)(&pb[l16][quad * 8]);

            // out^T: oacc[t] reg r = out[q=qrow][d = t*16 + quad*4 + r]
#pragma unroll
            for (int t = 0; t < 8; t++)
                oacc[t] = __builtin_amdgcn_mfma_f32_16x16x32_bf16(vfr[t], pfrag,
                                                                  oacc[t], 0, 0, 0);
        }
    }

    const float linv = 1.0f / lrow;
#pragma unroll
    for (int t = 0; t < 8; t++) {
        u16x4 ov;
#pragma unroll
        for (int r = 0; r < 4; r++) ov[r] = f2bf(oacc[t][r] * linv);
        *(u16x4*)&attn[(size_t)qrow * (NH * DV) + h * DV + t * 16 + quad * 4] = ov;
    }
}

// ---------------------------------------------------------------------------
extern "C" void kernel_launch(void* const* d_in, const int* in_sizes, int n_in,
                              void* d_out, int out_size, void* d_ws, size_t ws_size,
                              hipStream_t stream)
{
    const float* hid      = (const float*)d_in[0];
    // d_in[1] = position_ids (== arange(s)); sequence index used directly.
    const float* q_a_w    = (const float*)d_in[2];
    const float* q_a_ln_w = (const float*)d_in[3];
    const float* q_b_w    = (const float*)d_in[4];
    const float* kv_a_w   = (const float*)d_in[5];
    const float* kv_a_ln_w= (const float*)d_in[6];
    const float* kv_b_w   = (const float*)d_in[7];
    const float* o_w      = (const float*)d_in[8];

    const int NQKV = QR + KVR + DR;   // 2112: merged q_a_w ++ kv_a_w rows

    char* base = (char*)d_ws;
    u16* qkvaw_b = (u16*)(base + 0);          //  8,650,752  [2112,2048]
    u16* qbw_b   = (u16*)(base + 8650752);    //  9,437,184  [3072,1536]
    u16* kvbw_b  = (u16*)(base + 18087936);   //  4,194,304  [4096,512]
    u16* ow_b    = (u16*)(base + 22282240);   //  8,388,608  [2048,2048]
    u16* hid_b   = (u16*)(base + 30670848);   //  8,388,608  [2048,2048]
    u16* qkv_a   = (u16*)(base + 39059456);   //  8,650,752  [2048,2112]
    u16* q_n     = (u16*)(base + 47710208);   //  6,291,456  [2048,1536]
    u16* ckv     = (u16*)(base + 54001664);   //  2,097,152  [2048,512]
    u16* qb      = (u16*)(base + 56098816);   // 12,582,912  [2048,3072]
    u16* kvb     = (u16*)(base + 68681728);   // 16,777,216  [2048,4096]
    u16* Qb      = (u16*)(base + 85458944);   // 12,582,912  [16][2048][192]
    u16* Kb      = (u16*)(base + 98041856);   // 12,582,912
    u16* Vtb     = (u16*)(base + 110624768);  //  8,388,608  [16][128][2048]
    u16* attnb   = (u16*)(base + 39059456);   // reuse qkv_a (dead after rope)

    // 0) convert all f32 inputs/weights to bf16 in ONE launch.
    // max elems = q_b_w 4,718,592 -> 4608 blocks of 1024 elems.
    cvt_multi<<<dim3(4608, 6), 256, 0, stream>>>(
        hid,    hid_b,                          HIDDEN_ * S_LEN,
        q_a_w,  qkvaw_b,                        QR * HIDDEN_,
        kv_a_w, qkvaw_b + (size_t)QR * HIDDEN_, (KVR + DR) * HIDDEN_,
        q_b_w,  qbw_b,                          NH * DQK * QR,
        kv_b_w, kvbw_b,                         NH * 256 * KVR,
        o_w,    ow_b,                           HIDDEN_ * NH * DV);

    // 1) qkv_a = hidden @ [q_a_w; kv_a_w]^T   [2048,2112]
    gemm_bt<<<dim3((NQKV + 127) / 128, S_LEN / 128), 256, 0, stream>>>(
        hid_b, qkvaw_b, qkv_a, S_LEN, NQKV, HIDDEN_, 0);
    // 2+3) both RMSNorms in one launch
    rmsnorm2_k<<<dim3(S_LEN, 2), 256, 0, stream>>>(
        qkv_a, q_a_ln_w, q_n, qkv_a + QR, kv_a_ln_w, ckv, NQKV);
    // 4) qb = q_n @ q_b_w^T           [2048,3072]
    gemm_bt<<<dim3(NH * DQK / 128, S_LEN / 128), 256, 0, stream>>>(
        q_n, qbw_b, qb, S_LEN, NH * DQK, QR, 0);
    // 5) kvb = ckv @ kv_b_w^T         [2048,4096]
    gemm_bt<<<dim3(NH * 256 / 128, S_LEN / 128), 256, 0, stream>>>(
        ckv, kvbw_b, kvb, S_LEN, NH * 256, KVR, 0);
    // 6) rope + repack Q/K (k_pe = qkv_a cols 2048..2111)
    rope_repack<<<S_LEN, 256, 0, stream>>>(qb, kvb, qkv_a + QR + KVR, NQKV, Qb, Kb);
    // 6b) V transpose: Vt[h][d][s]
    transpose_v<<<dim3(S_LEN / 64, DV / 64, NH), 256, 0, stream>>>(kvb, Vtb);
    // 7) causal flash attention -> attnb [2048, 2048]
    mla_attn<<<dim3(32, NH), 256, 0, stream>>>(Qb, Kb, Vtb, attnb);
    // 8) out = attnb @ o_w^T          [2048,2048], f32 output
    gemm_bt<<<dim3(HIDDEN_ / 128, S_LEN / 128), 256, 0, stream>>>(
        attnb, ow_b, (float*)d_out, S_LEN, HIDDEN_, HIDDEN_, 1);
}

// Round 9
// 364.385 us; speedup vs baseline: 1.6688x; 1.1045x over previous
//
#include <hip/hip_runtime.h>
#include <stdint.h>

#define S_LEN 2048
#define HIDDEN_ 2048
#define NH 16
#define QR 1536
#define KVR 512
#define DN 128
#define DR 64
#define DQK 192
#define DV 128

typedef __attribute__((ext_vector_type(8))) short bf16x8;
typedef __attribute__((ext_vector_type(4))) float f32x4;
typedef __attribute__((ext_vector_type(4))) unsigned short u16x4;
typedef unsigned short u16;
typedef unsigned int u32;

#define GLOAD_LDS16(g, l)                                                      \
    __builtin_amdgcn_global_load_lds(                                          \
        (const __attribute__((address_space(1))) void*)(g),                    \
        (__attribute__((address_space(3))) void*)(l), 16, 0, 0)

__device__ inline float bf2f(u16 x) {
    union { u32 u; float f; } v; v.u = ((u32)x) << 16; return v.f;
}
__device__ inline u16 f2bf(float f) {
    union { float f; u32 u; } v; v.f = f;
    u32 u = v.u;
    return (u16)((u + 0x7fffu + ((u >> 16) & 1u)) >> 16);
}

// ---------------------------------------------------------------------------
// Merged f32 -> bf16 conversion: one launch, grid.y selects tensor.
// ---------------------------------------------------------------------------
__global__ void cvt_multi(const float* s0, u16* d0, int n0,
                          const float* s1, u16* d1, int n1,
                          const float* s2, u16* d2, int n2,
                          const float* s3, u16* d3, int n3,
                          const float* s4, u16* d4, int n4,
                          const float* s5, u16* d5, int n5)
{
    const float* src; u16* dst; int n;
    switch (blockIdx.y) {
        case 0: src = s0; dst = d0; n = n0; break;
        case 1: src = s1; dst = d1; n = n1; break;
        case 2: src = s2; dst = d2; n = n2; break;
        case 3: src = s3; dst = d3; n = n3; break;
        case 4: src = s4; dst = d4; n = n4; break;
        default: src = s5; dst = d5; n = n5; break;
    }
    int i = (blockIdx.x * 256 + threadIdx.x) * 4;
    if (i + 3 < n) {
        float4 v = *(const float4*)(src + i);
        dst[i + 0] = f2bf(v.x);
        dst[i + 1] = f2bf(v.y);
        dst[i + 2] = f2bf(v.z);
        dst[i + 3] = f2bf(v.w);
    }
}

// ---------------------------------------------------------------------------
// GEMM body: C[M,N] = A[M,K] @ B[N,K]^T, f32 accumulate, bf16 or f32 out.
// global_load_lds width-16 staging, 128x128 tile, BK=32.
// ---------------------------------------------------------------------------
__device__ __forceinline__
void gemm_body(const u16* __restrict__ A, const u16* __restrict__ B,
               void* __restrict__ Cv, int M, int N, int K, int out_f32,
               int bx, int by)
{
    __shared__ u16 sA[128 * 32];
    __shared__ u16 sB[128 * 32];
    const int tid  = threadIdx.x;
    const int wave = tid >> 6;
    const int lane = tid & 63;
    const int l16  = lane & 15;
    const int quad = lane >> 4;
    const int m_blk = by * 128;
    const int n_blk = bx * 128;
    const int wm = (wave >> 1) * 64;
    const int wn = (wave & 1) * 64;

    const f32x4 zero4 = {0.f, 0.f, 0.f, 0.f};
    f32x4 acc[4][4];
#pragma unroll
    for (int i = 0; i < 4; i++)
#pragma unroll
        for (int j = 0; j < 4; j++) acc[i][j] = zero4;

    const int srow = lane >> 2;
    const int scol = (lane & 3) * 8;

    for (int k0 = 0; k0 < K; k0 += 32) {
        __syncthreads();
#pragma unroll
        for (int p = 0; p < 2; p++) {
            const int rbase = wave * 32 + p * 16;
            const int row = rbase + srow;
            const u16* ga = A + (size_t)(m_blk + row) * K + k0 + scol;
            GLOAD_LDS16(ga, &sA[rbase * 32]);
            int brow = n_blk + row; if (brow >= N) brow = N - 1;
            const u16* gb = B + (size_t)brow * K + k0 + scol;
            GLOAD_LDS16(gb, &sB[rbase * 32]);
        }
        __syncthreads();

        bf16x8 af[4], bfr[4];
#pragma unroll
        for (int i = 0; i < 4; i++)
            af[i] = *(const bf16x8*)(sA + (wm + i * 16 + l16) * 32 + quad * 8);
#pragma unroll
        for (int j = 0; j < 4; j++)
            bfr[j] = *(const bf16x8*)(sB + (wn + j * 16 + l16) * 32 + quad * 8);
#pragma unroll
        for (int i = 0; i < 4; i++)
#pragma unroll
            for (int j = 0; j < 4; j++)
                acc[i][j] = __builtin_amdgcn_mfma_f32_16x16x32_bf16(
                    af[i], bfr[j], acc[i][j], 0, 0, 0);
    }

#pragma unroll
    for (int i = 0; i < 4; i++)
#pragma unroll
        for (int j = 0; j < 4; j++)
#pragma unroll
            for (int r = 0; r < 4; r++) {
                int mrow = m_blk + wm + i * 16 + quad * 4 + r;
                int ncol = n_blk + wn + j * 16 + l16;
                if (ncol < N) {
                    if (out_f32)
                        ((float*)Cv)[(size_t)mrow * N + ncol] = acc[i][j][r];
                    else
                        ((u16*)Cv)[(size_t)mrow * N + ncol] = f2bf(acc[i][j][r]);
                }
            }
}

__global__ __launch_bounds__(256, 3)
void gemm_bt(const u16* __restrict__ A, const u16* __restrict__ B,
             void* __restrict__ Cv, int M, int N, int K, int out_f32)
{
    gemm_body(A, B, Cv, M, N, K, out_f32, blockIdx.x, blockIdx.y);
}

// Two independent GEMMs in one launch (z selects). z=0: N0 cols (grid.x may
// overshoot -> early exit), z=1: N1.
__global__ __launch_bounds__(256, 3)
void gemm_dual(const u16* A0, const u16* B0, u16* C0, int M0, int N0, int K0,
               const u16* A1, const u16* B1, u16* C1, int M1, int N1, int K1)
{
    if (blockIdx.z == 0) {
        if ((int)blockIdx.x >= (N0 + 127) / 128) return;
        gemm_body(A0, B0, C0, M0, N0, K0, 0, blockIdx.x, blockIdx.y);
    } else {
        gemm_body(A1, B1, C1, M1, N1, K1, 0, blockIdx.x, blockIdx.y);
    }
}

// ---------------------------------------------------------------------------
// Merged RMSNorm: grid (S_LEN, 2). y==0: q (len 1536), y==1: kv (len 512).
// ---------------------------------------------------------------------------
__global__ void rmsnorm2_k(const u16* __restrict__ X0, const float* __restrict__ W0,
                           u16* __restrict__ Y0,
                           const u16* __restrict__ X1, const float* __restrict__ W1,
                           u16* __restrict__ Y1, int in_stride)
{
    const u16* X; const float* W; u16* Y; int len, out_stride;
    if (blockIdx.y == 0) { X = X0; W = W0; Y = Y0; len = QR;  out_stride = QR; }
    else                 { X = X1; W = W1; Y = Y1; len = KVR; out_stride = KVR; }
    const int row = blockIdx.x;
    const u16* x = X + (size_t)row * in_stride;
    u16* y = Y + (size_t)row * out_stride;
    float ss = 0.f;
    for (int i = threadIdx.x; i < len; i += 256) { float v = bf2f(x[i]); ss += v * v; }
#pragma unroll
    for (int off = 32; off; off >>= 1) ss += __shfl_down(ss, off, 64);
    __shared__ float red[4];
    if ((threadIdx.x & 63) == 0) red[threadIdx.x >> 6] = ss;
    __syncthreads();
    float tot = red[0] + red[1] + red[2] + red[3];
    float inv = 1.0f / sqrtf(tot / (float)len + 1e-6f);
    for (int i = threadIdx.x; i < len; i += 256)
        y[i] = f2bf(W[i] * bf2f(x[i]) * inv);
}

// ---------------------------------------------------------------------------
// RoPE + repack Q/K into per-head contiguous layouts:
//   Q [H][S][192], K [H][S][192]
// ---------------------------------------------------------------------------
__global__ void rope_repack(const u16* __restrict__ q,      // [S][H*192]
                            const u16* __restrict__ kvb,    // [S][H*256]
                            const u16* __restrict__ kva_pe, // [S][*] stride kva_stride
                            int kva_stride,
                            u16* __restrict__ Q, u16* __restrict__ Kf)
{
    const int s = blockIdx.x;
    const float pos = (float)s;
    const int t = threadIdx.x;
    __shared__ float cs[64], sn[64];
    __shared__ u16 kpe_r[64];
    if (t < 64) {
        int jf = t & 31;
        float freq = powf(10000.f, -(float)(2 * jf) / 64.f);
        float ang = pos * freq;
        cs[t] = cosf(ang);
        sn[t] = sinf(ang);
    }
    __syncthreads();
    if (t < 64) {
        int j = t;
        float x = bf2f(kva_pe[(size_t)s * kva_stride + j]);
        float other = (j < 32) ? -bf2f(kva_pe[(size_t)s * kva_stride + j + 32])
                               :  bf2f(kva_pe[(size_t)s * kva_stride + j - 32]);
        kpe_r[j] = f2bf(x * cs[j] + other * sn[j]);
    }
    __syncthreads();

    for (int idx = t; idx < NH * DQK; idx += 256) {
        int h = idx / DQK, d = idx % DQK;
        const size_t qrow = (size_t)s * (NH * DQK) + h * DQK;
        u16 qv;
        if (d < DN) qv = q[qrow + d];
        else {
            int j = d - DN;
            float x = bf2f(q[qrow + DN + j]);
            float other = (j < 32) ? -bf2f(q[qrow + DN + j + 32])
                                   :  bf2f(q[qrow + DN + j - 32]);
            qv = f2bf(x * cs[j] + other * sn[j]);
        }
        Q[((size_t)h * S_LEN + s) * DQK + d] = qv;
        u16 kv;
        if (d < DN) kv = kvb[(size_t)s * (NH * 256) + h * 256 + d];
        else        kv = kpe_r[d - DN];
        Kf[((size_t)h * S_LEN + s) * DQK + d] = kv;
    }
}

// ---------------------------------------------------------------------------
// V transpose straight out of kvb: Vt[h][d][s] = kvb[s][h*256+128+d].
// ---------------------------------------------------------------------------
__global__ void transpose_v(const u16* __restrict__ kvb, u16* __restrict__ Vt)
{
    __shared__ u16 tile[64][72];
    const int h  = blockIdx.z;
    const int s0 = blockIdx.x * 64;
    const int d0 = blockIdx.y * 64;
    const int t  = threadIdx.x;
#pragma unroll
    for (int p = 0; p < 2; p++) {
        int c = p * 256 + t;
        int r = c >> 3, col = (c & 7) * 8;
        *(bf16x8*)&tile[r][col] =
            *(const bf16x8*)&kvb[(size_t)(s0 + r) * (NH * 256) + h * 256 + 128 + d0 + col];
    }
    __syncthreads();
#pragma unroll
    for (int p = 0; p < 2; p++) {
        int c = p * 256 + t;
        int dr = c >> 3, sc = (c & 7) * 8;
        bf16x8 v;
#pragma unroll
        for (int j = 0; j < 8; j++) v[j] = (short)tile[sc + j][dr];
        *(bf16x8*)&Vt[((size_t)h * DV + d0 + dr) * S_LEN + s0 + sc] = v;
    }
}

// ---------------------------------------------------------------------------
// Causal flash attention, S^T-layout softmax, SPLIT-K (flash-decoding).
// Grid (48, NH). Block map (big-first for backfill):
//   bx  0..15: s = 16+bx,  tiles [0,32)        -> partial chunk 0
//   bx 16..31: s = 47-bx,  tiles [32, 2s+2)    -> partial chunk 1
//   bx 32..47: s = 47-bx,  tiles [0, 2s+2)     -> direct store (s<16)
// Critical path = 32 tiles (was 64). Partials: O f32[64][128] + m[64] + l[64]
// per (h, s-16, chunk), merged by attn_combine.
// Tile body identical to the verified round-6 kernel.
// ---------------------------------------------------------------------------
__global__ __launch_bounds__(256, 2)
void mla_attn(const u16* __restrict__ Q, const u16* __restrict__ Kf,
              const u16* __restrict__ Vt, u16* __restrict__ attn,
              float* __restrict__ part)
{
    const int h  = blockIdx.y;
    const int bx = blockIdx.x;
    int s, tb, te, cIdx; bool direct;
    if (bx < 16)      { s = 16 + bx; tb = 0;  te = 32;        cIdx = 0; direct = false; }
    else if (bx < 32) { s = 47 - bx; tb = 32; te = 2 * s + 2; cIdx = 1; direct = false; }
    else              { s = 47 - bx; tb = 0;  te = 2 * s + 2; cIdx = 0; direct = true;  }

    const int wave  = threadIdx.x >> 6;
    const int lane  = threadIdx.x & 63;
    const int l16   = lane & 15;
    const int quad  = lane >> 4;
    const int q0    = s * 64 + wave * 16;
    const int qrow  = q0 + l16;

    const u16* Qh  = Q  + (size_t)h * S_LEN * DQK;
    const u16* Kh  = Kf + (size_t)h * S_LEN * DQK;
    const u16* Vth = Vt + (size_t)h * DV * S_LEN;

    __shared__ u16 sK[2][24 * 32 * 8];    // 2 x 12 KB
    __shared__ u16 sV[2][4 * 128 * 8];    // 2 x  8 KB
    __shared__ u16 pbuf[4][16][36];       // 4.5 KB
    u16 (*pb)[36] = pbuf[wave];

    bf16x8 qf[6];
#pragma unroll
    for (int st = 0; st < 6; st++)
        qf[st] = *(const bf16x8*)(Qh + (size_t)qrow * DQK + st * 32 + quad * 8);

    const f32x4 zero4 = {0.f, 0.f, 0.f, 0.f};
    f32x4 oacc[8];
#pragma unroll
    for (int t = 0; t < 8; t++) oacc[t] = zero4;
    float mrow = -INFINITY, lrow = 0.f;

    const float scale = 0.07216878364870323f;  // 192^-0.5

    auto stage = [&](int buf, int c0) {
#pragma unroll
        for (int g = 0; g < 3; g++) {
            int c = g * 256 + wave * 64 + lane;
            int row = c & 31, cg = c >> 5;
            GLOAD_LDS16(Kh + (size_t)(c0 + row) * DQK + cg * 8,
                        &sK[buf][(g * 256 + wave * 64) * 8]);
        }
#pragma unroll
        for (int g = 0; g < 2; g++) {
            int c = g * 256 + wave * 64 + lane;
            int d = c & 127, cg = c >> 7;
            GLOAD_LDS16(Vth + (size_t)d * S_LEN + c0 + cg * 8,
                        &sV[buf][(g * 256 + wave * 64) * 8]);
        }
    };

    stage(0, tb * 32);   // prologue

    for (int kt = tb; kt < te; kt++) {
        const int c0  = kt * 32;
        const int cur = (kt - tb) & 1;
        __syncthreads();
        if (kt + 1 < te) stage(cur ^ 1, c0 + 32);

        if (c0 <= q0 + 15) {
            f32x4 s0 = zero4, s1 = zero4;
#pragma unroll
            for (int st = 0; st < 6; st++) {
                bf16x8 k0 = *(const bf16x8*)&sK[cur][((st * 4 + quad) * 32 + l16) * 8];
                bf16x8 k1 = *(const bf16x8*)&sK[cur][((st * 4 + quad) * 32 + 16 + l16) * 8];
                s0 = __builtin_amdgcn_mfma_f32_16x16x32_bf16(k0, qf[st], s0, 0, 0, 0);
                s1 = __builtin_amdgcn_mfma_f32_16x16x32_bf16(k1, qf[st], s1, 0, 0, 0);
            }
            bf16x8 vfr[8];
#pragma unroll
            for (int t = 0; t < 8; t++)
                vfr[t] = *(const bf16x8*)&sV[cur][(quad * 128 + t * 16 + l16) * 8];

            const bool full = (c0 + 31 <= q0);
            float v0[4], v1[4];
#pragma unroll
            for (int r = 0; r < 4; r++) {
                v0[r] = s0[r] * scale;
                v1[r] = s1[r] * scale;
                if (!full) {
                    if (c0 + quad * 4 + r > qrow)      v0[r] = -INFINITY;
                    if (c0 + 16 + quad * 4 + r > qrow) v1[r] = -INFINITY;
                }
            }
            float lm = fmaxf(fmaxf(fmaxf(v0[0], v0[1]), fmaxf(v0[2], v0[3])),
                             fmaxf(fmaxf(v1[0], v1[1]), fmaxf(v1[2], v1[3])));
            lm = fmaxf(lm, __shfl_xor(lm, 16, 64));
            lm = fmaxf(lm, __shfl_xor(lm, 32, 64));
            const float mnew  = fmaxf(mrow, lm);
            const float alpha = __expf(mrow - mnew);
            float p0[4], p1[4], rs = 0.f;
#pragma unroll
            for (int r = 0; r < 4; r++) {
                p0[r] = __expf(v0[r] - mnew);
                p1[r] = __expf(v1[r] - mnew);
                rs += p0[r] + p1[r];
            }
            rs += __shfl_xor(rs, 16, 64);
            rs += __shfl_xor(rs, 32, 64);
            lrow = lrow * alpha + rs;
            mrow = mnew;
#pragma unroll
            for (int t = 0; t < 8; t++) oacc[t] *= alpha;

            u16x4 pk0, pk1;
#pragma unroll
            for (int r = 0; r < 4; r++) { pk0[r] = f2bf(p0[r]); pk1[r] = f2bf(p1[r]); }
            *(u16x4*)&pb[l16][quad * 4]      = pk0;
            *(u16x4*)&pb[l16][16 + quad * 4] = pk1;
            asm volatile("s_waitcnt lgkmcnt(0)" ::: "memory");
            bf16x8 pfrag = *(const bf16x8*)(&pb[l16][quad * 8]);

#pragma unroll
            for (int t = 0; t < 8; t++)
                oacc[t] = __builtin_amdgcn_mfma_f32_16x16x32_bf16(vfr[t], pfrag,
                                                                  oacc[t], 0, 0, 0);
        }
    }

    if (direct) {
        const float linv = 1.0f / lrow;
#pragma unroll
        for (int t = 0; t < 8; t++) {
            u16x4 ov;
#pragma unroll
            for (int r = 0; r < 4; r++) ov[r] = f2bf(oacc[t][r] * linv);
            *(u16x4*)&attn[(size_t)qrow * (NH * DV) + h * DV + t * 16 + quad * 4] = ov;
        }
    } else {
        // partial record: 8320 f32 = O[64][128] ++ m[64] ++ l[64]
        float* pout = part + ((size_t)(h * 16 + (s - 16)) * 2 + cIdx) * 8320;
        const int rowl = wave * 16 + l16;
#pragma unroll
        for (int t = 0; t < 8; t++) {
            float4 ov = {oacc[t][0], oacc[t][1], oacc[t][2], oacc[t][3]};
            *(float4*)&pout[(size_t)rowl * 128 + t * 16 + quad * 4] = ov;
        }
        if (quad == 0) {
            pout[8192 + rowl] = mrow;
            pout[8256 + rowl] = lrow;
        }
    }
}

// ---------------------------------------------------------------------------
// Merge the two split-K partials for strips s=16..31.
// Grid (16, NH), 256 threads.
// ---------------------------------------------------------------------------
__global__ void attn_combine(const float* __restrict__ part, u16* __restrict__ attn)
{
    const int h = blockIdx.y, sIdx = blockIdx.x;
    const int s = 16 + sIdx;
    const float* p0 = part + ((size_t)(h * 16 + sIdx) * 2 + 0) * 8320;
    const float* p1 = p0 + 8320;
    for (int e = threadIdx.x; e < 8192; e += 256) {
        int row = e >> 7, d = e & 127;
        float m0 = p0[8192 + row], m1 = p1[8192 + row];
        float l0 = p0[8256 + row], l1 = p1[8256 + row];
        float M  = fmaxf(m0, m1);
        float w0 = __expf(m0 - M), w1 = __expf(m1 - M);
        float o  = (w0 * p0[e] + w1 * p1[e]) / (w0 * l0 + w1 * l1);
        attn[(size_t)(s * 64 + row) * (NH * DV) + h * DV + d] = f2bf(o);
    }
}

// ---------------------------------------------------------------------------
extern "C" void kernel_launch(void* const* d_in, const int* in_sizes, int n_in,
                              void* d_out, int out_size, void* d_ws, size_t ws_size,
                              hipStream_t stream)
{
    const float* hid      = (const float*)d_in[0];
    // d_in[1] = position_ids (== arange(s)); sequence index used directly.
    const float* q_a_w    = (const float*)d_in[2];
    const float* q_a_ln_w = (const float*)d_in[3];
    const float* q_b_w    = (const float*)d_in[4];
    const float* kv_a_w   = (const float*)d_in[5];
    const float* kv_a_ln_w= (const float*)d_in[6];
    const float* kv_b_w   = (const float*)d_in[7];
    const float* o_w      = (const float*)d_in[8];

    const int NQKV = QR + KVR + DR;   // 2112: merged q_a_w ++ kv_a_w rows

    char* base = (char*)d_ws;
    u16* qkvaw_b = (u16*)(base + 0);          //  8,650,752  [2112,2048]
    u16* qbw_b   = (u16*)(base + 8650752);    //  9,437,184  [3072,1536]
    u16* kvbw_b  = (u16*)(base + 18087936);   //  4,194,304  [4096,512]
    u16* ow_b    = (u16*)(base + 22282240);   //  8,388,608  [2048,2048]
    u16* hid_b   = (u16*)(base + 30670848);   //  8,388,608  [2048,2048]
    u16* qkv_a   = (u16*)(base + 39059456);   //  8,650,752  [2048,2112]
    u16* q_n     = (u16*)(base + 47710208);   //  6,291,456  [2048,1536]
    u16* ckv     = (u16*)(base + 54001664);   //  2,097,152  [2048,512]
    u16* qb      = (u16*)(base + 56098816);   // 12,582,912  [2048,3072]
    u16* kvb     = (u16*)(base + 68681728);   // 16,777,216  [2048,4096]
    u16* Qb      = (u16*)(base + 85458944);   // 12,582,912  [16][2048][192]
    u16* Kb      = (u16*)(base + 98041856);   // 12,582,912
    u16* Vtb     = (u16*)(base + 110624768);  //  8,388,608  [16][128][2048]
    u16* attnb   = (u16*)(base + 39059456);   // reuse qkv_a (dead after rope)
    // split-K partials: 512 records x 8320 f32 = 17,039,360 B,
    // placed over qb+kvb (both dead once attention runs)
    float* partb = (float*)(base + 56098816);

    // 0) convert all f32 inputs/weights to bf16 in ONE launch.
    cvt_multi<<<dim3(4608, 6), 256, 0, stream>>>(
        hid,    hid_b,                          HIDDEN_ * S_LEN,
        q_a_w,  qkvaw_b,                        QR * HIDDEN_,
        kv_a_w, qkvaw_b + (size_t)QR * HIDDEN_, (KVR + DR) * HIDDEN_,
        q_b_w,  qbw_b,                          NH * DQK * QR,
        kv_b_w, kvbw_b,                         NH * 256 * KVR,
        o_w,    ow_b,                           HIDDEN_ * NH * DV);

    // 1) qkv_a = hidden @ [q_a_w; kv_a_w]^T   [2048,2112]
    gemm_bt<<<dim3((NQKV + 127) / 128, S_LEN / 128), 256, 0, stream>>>(
        hid_b, qkvaw_b, qkv_a, S_LEN, NQKV, HIDDEN_, 0);
    // 2+3) both RMSNorms in one launch
    rmsnorm2_k<<<dim3(S_LEN, 2), 256, 0, stream>>>(
        qkv_a, q_a_ln_w, q_n, qkv_a + QR, kv_a_ln_w, ckv, NQKV);
    // 4+5) qb = q_n @ q_b_w^T [2048,3072]  and  kvb = ckv @ kv_b_w^T [2048,4096]
    //      in ONE launch (z-switch; 896 active blocks)
    gemm_dual<<<dim3(32, S_LEN / 128, 2), 256, 0, stream>>>(
        q_n, qbw_b, qb,  S_LEN, NH * DQK, QR,
        ckv, kvbw_b, kvb, S_LEN, NH * 256, KVR);
    // 6) rope + repack Q/K (k_pe = qkv_a cols 2048..2111)
    rope_repack<<<S_LEN, 256, 0, stream>>>(qb, kvb, qkv_a + QR + KVR, NQKV, Qb, Kb);
    // 6b) V transpose: Vt[h][d][s]
    transpose_v<<<dim3(S_LEN / 64, DV / 64, NH), 256, 0, stream>>>(kvb, Vtb);
    // 7) causal flash attention (split-K) -> attnb + partials
    mla_attn<<<dim3(48, NH), 256, 0, stream>>>(Qb, Kb, Vtb, attnb, partb);
    // 7b) merge partials for strips 16..31
    attn_combine<<<dim3(16, NH), 256, 0, stream>>>(partb, attnb);
    // 8) out = attnb @ o_w^T          [2048,2048], f32 output
    gemm_bt<<<dim3(HIDDEN_ / 128, S_LEN / 128), 256, 0, stream>>>(
        attnb, ow_b, (float*)d_out, S_LEN, HIDDEN_, HIDDEN_, 1);
}